// Round 2
// baseline (1614.515 us; speedup 1.0000x reference)
//
#include <hip/hip_runtime.h>
#include <hip/hip_bf16.h>
#include <cstdint>
#include <cstddef>

// Problem constants (B,T,C,H,D) = (2, 2048, 4096, 32, 128)
#define BB 2
#define TT 2048
#define CC 4096
#define HH 32
#define DD 128
#define MM (BB*TT)   // 4096 rows for all GEMMs

typedef __bf16 bf16;
typedef __bf16 bf16x8 __attribute__((ext_vector_type(8)));
typedef __bf16 bf16x4 __attribute__((ext_vector_type(4)));
typedef float  f32x4  __attribute__((ext_vector_type(4)));

__device__ __forceinline__ void async_copy16(const bf16* g, bf16* l) {
  __builtin_amdgcn_global_load_lds(
      (const __attribute__((address_space(1))) void*)g,
      (__attribute__((address_space(3))) void*)l, 16, 0, 0);
}

// ---------------------------------------------------------------------------
// fp32 -> bf16 convert (hidden_states).
// ---------------------------------------------------------------------------
__global__ __launch_bounds__(256) void conv_k(const float* __restrict__ X,
                                              bf16* __restrict__ Y)
{
  const size_t i = ((size_t)blockIdx.x * 256 + threadIdx.x) * 8;
  const float4 a = *(const float4*)(X + i);
  const float4 b = *(const float4*)(X + i + 4);
  bf16x8 w;
  w[0] = (bf16)a.x; w[1] = (bf16)a.y; w[2] = (bf16)a.z; w[3] = (bf16)a.w;
  w[4] = (bf16)b.x; w[5] = (bf16)b.y; w[6] = (bf16)b.z; w[7] = (bf16)b.w;
  *(bf16x8*)(Y + i) = w;
}

// ---------------------------------------------------------------------------
// W [K,N] fp32 -> Wt [N,K] bf16.  64x64 tile through LDS.
// ---------------------------------------------------------------------------
__global__ __launch_bounds__(256) void transpose_k(const float* __restrict__ W,
                                                   bf16* __restrict__ Wt)
{
  __shared__ bf16 Tl[64][72];
  const int tid = threadIdx.x;
  const int k0 = blockIdx.x * 64, n0 = blockIdx.y * 64;
  #pragma unroll
  for (int it = 0; it < 4; it++) {
    int idx = it * 256 + tid;          // 0..1023
    int kr  = idx >> 4;                // 0..63
    int nc  = (idx & 15) * 4;
    float4 v = *(const float4*)(W + (size_t)(k0 + kr) * CC + n0 + nc);
    Tl[nc + 0][kr] = (bf16)v.x;
    Tl[nc + 1][kr] = (bf16)v.y;
    Tl[nc + 2][kr] = (bf16)v.z;
    Tl[nc + 3][kr] = (bf16)v.w;
  }
  __syncthreads();
  #pragma unroll
  for (int it = 0; it < 2; it++) {
    int idx = it * 256 + tid;          // 0..511
    int nr  = idx >> 3;                // 0..63
    int kc  = (idx & 7) * 8;
    bf16x8 v = *(const bf16x8*)&Tl[nr][kc];
    *(bf16x8*)(Wt + (size_t)(n0 + nr) * CC + k0 + kc) = v;
  }
}

// ---------------------------------------------------------------------------
// GEMM: C[M,N=4096] = A[M,K] @ Bt[N,K]^T, both bf16, MFMA 16x16x32.
// m97 structure: 128x128 tile, BK=32, global_load_lds width-16 staging.
// EPI: 0 = RoPE + bf16 [M,C]; 1 = bf16 transposed per head -> vt[B,H,D,T];
//      2 = fp32 [M,C] (final output)
// ---------------------------------------------------------------------------
template<int EPI>
__global__ __launch_bounds__(256) void gemm_k(
    const bf16* __restrict__ A, const bf16* __restrict__ Bt,
    void* __restrict__ Out, const float* __restrict__ sinp,
    const float* __restrict__ cosp)
{
  constexpr int N = CC, K = CC;
  __shared__ bf16 Al[128 * 32];
  __shared__ bf16 Bl[128 * 32];

  const int tid  = threadIdx.x;
  const int wave = tid >> 6, lane = tid & 63;
  const int lr   = lane & 15, quad = lane >> 4;
  const int m0   = blockIdx.y * 128, n0 = blockIdx.x * 128;
  const int wm   = (wave >> 1) * 64, wn = (wave & 1) * 64;

  const int srow = lane >> 2;          // 0..15
  const int scol = (lane & 3) * 8;     // 0,8,16,24

  f32x4 acc[4][4];
  #pragma unroll
  for (int i = 0; i < 4; i++)
    #pragma unroll
    for (int j = 0; j < 4; j++) acc[i][j] = f32x4{0.f, 0.f, 0.f, 0.f};

  for (int k0 = 0; k0 < K; k0 += 32) {
    __syncthreads();
    #pragma unroll
    for (int s = 0; s < 2; s++) {
      const int chunk = s * 4 + wave;
      const int row   = chunk * 16 + srow;
      async_copy16(A  + (size_t)(m0 + row) * K + k0 + scol, Al + chunk * 512 + lane * 8);
      async_copy16(Bt + (size_t)(n0 + row) * K + k0 + scol, Bl + chunk * 512 + lane * 8);
    }
    __syncthreads();

    bf16x8 af[4], bfv[4];
    #pragma unroll
    for (int i = 0; i < 4; i++) af[i]  = *(const bf16x8*)&Al[(wm + 16 * i + lr) * 32 + quad * 8];
    #pragma unroll
    for (int j = 0; j < 4; j++) bfv[j] = *(const bf16x8*)&Bl[(wn + 16 * j + lr) * 32 + quad * 8];
    #pragma unroll
    for (int i = 0; i < 4; i++)
      #pragma unroll
      for (int j = 0; j < 4; j++)
        acc[i][j] = __builtin_amdgcn_mfma_f32_16x16x32_bf16(af[i], bfv[j], acc[i][j], 0, 0, 0);
  }

  // ---- epilogue: C/D layout col = lane&15, row = quad*4 + r ----
  #pragma unroll
  for (int i = 0; i < 4; i++) {
    int grow = m0 + wm + 16 * i + quad * 4;
    #pragma unroll
    for (int j = 0; j < 4; j++) {
      int gc = n0 + wn + 16 * j + lr;
      if (EPI == 0) {
        bf16* outp = (bf16*)Out;
        int dh = gc & (DD - 1);
        float sgn = (gc & 1) ? 1.0f : -1.0f;
        #pragma unroll
        for (int r = 0; r < 4; r++) {
          float x  = acc[i][j][r];
          float xp = __shfl_xor(x, 1, 64);
          int t = (grow + r) & (TT - 1);
          float s = sinp[t * DD + dh];
          float c = cosp[t * DD + dh];
          outp[(size_t)(grow + r) * N + gc] = (bf16)(x * c + sgn * xp * s);
        }
      } else if (EPI == 1) {
        bf16* outp = (bf16*)Out;
        int hh = gc >> 7, dh = gc & (DD - 1);
        int bidx = grow >> 11, t = grow & (TT - 1);
        bf16x4 w;
        #pragma unroll
        for (int r = 0; r < 4; r++) w[r] = (bf16)acc[i][j][r];
        *(bf16x4*)(outp + (((size_t)bidx * HH + hh) * DD + dh) * TT + t) = w;
      } else {
        float* outp = (float*)Out;
        #pragma unroll
        for (int r = 0; r < 4; r++)
          outp[(size_t)(grow + r) * N + gc] = acc[i][j][r];
      }
    }
  }
}

// ---------------------------------------------------------------------------
// Flash attention v4: 4 waves/block, 64 q-rows/block (16 per wave),
// 64-key K tiles DOUBLE-BUFFERED in LDS (global_load_lds, prefetch-early,
// one barrier/tile).  V is NOT staged: per-(b,h) V is L2-resident (512 KB,
// shared by 32 q-blocks), so PV B-fragments are direct 16B/lane global
// loads, register-preloaded in two batches (before QK^T / before softmax)
// so ~600 cyc of compute hides their latency (T14 issue-early).
// Softmax: exp2-domain, lane-local deferred-max guard, row-sum via
// all-ones MFMA.  XOR-swizzled Kl (16B granule) for conflict-free frags.
// ---------------------------------------------------------------------------
__global__ __launch_bounds__(256) void attn_k(
    const bf16* __restrict__ qb, const bf16* __restrict__ kb,
    const bf16* __restrict__ vt, bf16* __restrict__ ao)
{
  const int tid  = threadIdx.x;
  const int wave = tid >> 6, lane = tid & 63;
  const int lr   = lane & 15, quad = lane >> 4;
  const int qblk = blockIdx.x * 64;
  const int q0   = qblk + wave * 16;       // this wave's 16 q-rows
  const int h    = blockIdx.y, b = blockIdx.z;

  // Kl[sel] row k (256B): slot s (16B) holds K[k][(s ^ (k&15))*8 ..]
  __shared__ bf16 Kl[2][64 * 128];
  __shared__ bf16 Pl[4][16][72];           // per-wave P (16B-aligned rows)

  // Q fragments (A-layout): lane holds Q[q0+lr][quad*8+j + 32*ds]
  bf16x8 qf[4];
  const bf16* qrow = qb + ((size_t)(b * TT + q0 + lr) * HH + h) * DD;
  #pragma unroll
  for (int ds = 0; ds < 4; ds++) qf[ds] = *(const bf16x8*)(qrow + ds * 32 + quad * 8);

  float m_r[4];
  f32x4 lacc;                              // row-sum accumulator (via ones-MFMA)
  f32x4 oacc[8];
  #pragma unroll
  for (int r = 0; r < 4; r++) { m_r[r] = -1e30f; lacc[r] = 0.f; }
  #pragma unroll
  for (int dc = 0; dc < 8; dc++) oacc[dc] = f32x4{0.f, 0.f, 0.f, 0.f};

  const int jt_end = blockIdx.x;           // inclusive (causal)
  const float sc2 = 0.12753861f;           // (1/sqrt(128)) * log2(e)

  const bf16* kbase = kb + ((size_t)(b * TT) * HH + h) * DD;
  const bf16* vbase = vt + ((size_t)b * HH + h) * DD * TT;

  // K staging geometry (per wave, 4 instrs):
  const int k_row_in = lane >> 4;          // 0..3   (4 rows of 256B per chunk)
  const int k_slot   = lane & 15;

  auto stageK = [&](int sel, int jt) {
    const int k0 = jt * 64;
    #pragma unroll
    for (int s = 0; s < 4; s++) {
      const int ch   = s * 4 + wave;       // 0..15
      const int krow = ch * 4 + k_row_in;  // 0..63
      const int kcol = (k_slot ^ (krow & 15)) * 8;
      async_copy16(kbase + (size_t)(k0 + krow) * (HH * DD) + kcol,
                   &Kl[sel][ch * 512 + lane * 8]);
    }
  };

  bf16x8 ones;
  #pragma unroll
  for (int t = 0; t < 8; t++) ones[t] = (bf16)1.0f;

  // prologue: stage tile 0, drain.
  stageK(0, 0);
  __syncthreads();

  for (int jt = 0; jt <= jt_end; jt++) {
    const int cur = jt & 1;
    const int k0 = jt * 64;
    const bf16* vcol = vbase + k0;         // + d*TT + ks*32 + quad*8

    // ---- V preload batch 0 (dc 0..3): issued before QK^T, used in PV ----
    bf16x8 vfr[8][2];
    #pragma unroll
    for (int dc = 0; dc < 4; dc++) {
      const int d = dc * 16 + lr;
      #pragma unroll
      for (int ks = 0; ks < 2; ks++)
        vfr[dc][ks] = *(const bf16x8*)(vcol + (size_t)d * TT + ks * 32 + quad * 8);
    }

    if (jt < jt_end) stageK(cur ^ 1, jt + 1);   // prefetch next K tile

    // ---- QK^T: 4 key groups of 16 ----
    f32x4 sacc[4];
    #pragma unroll
    for (int kk = 0; kk < 4; kk++) sacc[kk] = f32x4{0.f, 0.f, 0.f, 0.f};
    __builtin_amdgcn_s_setprio(1);
    #pragma unroll
    for (int ds = 0; ds < 4; ds++) {
      #pragma unroll
      for (int kk = 0; kk < 4; kk++) {
        const int key  = 16 * kk + lr;
        const int slot = (ds * 4 + quad) ^ lr;        // lr == key&15
        bf16x8 kf = *(const bf16x8*)&Kl[cur][key * 128 + slot * 8];
        sacc[kk] = __builtin_amdgcn_mfma_f32_16x16x32_bf16(qf[ds], kf, sacc[kk], 0, 0, 0);
      }
    }
    __builtin_amdgcn_s_setprio(0);

    // ---- V preload batch 1 (dc 4..7): latency covered by softmax ----
    #pragma unroll
    for (int dc = 4; dc < 8; dc++) {
      const int d = dc * 16 + lr;
      #pragma unroll
      for (int ks = 0; ks < 2; ks++)
        vfr[dc][ks] = *(const bf16x8*)(vcol + (size_t)d * TT + ks * 32 + quad * 8);
    }

    // ---- softmax (raw-score domain; exp2 with folded scale) ----
    const int qr = q0 + quad * 4;
    float v[4][4], lmx[4];
    if (jt == jt_end) {                    // only the diagonal tile masks
      #pragma unroll
      for (int r = 0; r < 4; r++)
        #pragma unroll
        for (int kk = 0; kk < 4; kk++) {
          float x = sacc[kk][r];
          if (k0 + 16 * kk + lr > qr + r) x = -1e30f;
          v[r][kk] = x;
        }
    } else {
      #pragma unroll
      for (int r = 0; r < 4; r++)
        #pragma unroll
        for (int kk = 0; kk < 4; kk++) v[r][kk] = sacc[kk][r];
    }
    bool need = false;
    #pragma unroll
    for (int r = 0; r < 4; r++) {
      lmx[r] = fmaxf(fmaxf(v[r][0], v[r][1]), fmaxf(v[r][2], v[r][3]));
      need = need || (lmx[r] > m_r[r] + 24.0f);   // e bounded by 2^(24*sc2)≈8.4
    }
    if (__any(need)) {                     // rare: full reduce + rescale
      #pragma unroll
      for (int r = 0; r < 4; r++) {
        float mx = lmx[r];
        #pragma unroll
        for (int off = 1; off < 16; off <<= 1) mx = fmaxf(mx, __shfl_xor(mx, off, 64));
        float mn = fmaxf(m_r[r], mx);
        float al = __builtin_amdgcn_exp2f((m_r[r] - mn) * sc2);
        lacc[r] *= al;
        #pragma unroll
        for (int dc = 0; dc < 8; dc++) oacc[dc][r] *= al;
        m_r[r] = mn;
      }
    }
    #pragma unroll
    for (int r = 0; r < 4; r++) {
      const float mb = m_r[r] * sc2;
      #pragma unroll
      for (int kk = 0; kk < 4; kk++) {
        float e = __builtin_amdgcn_exp2f(__builtin_fmaf(v[r][kk], sc2, -mb));
        Pl[wave][quad * 4 + r][kk * 16 + lr] = (bf16)e;
      }
    }

    // wave-private P: only in-wave DS ordering needed (no block barrier)
    asm volatile("s_waitcnt lgkmcnt(0)" ::: "memory");
    __builtin_amdgcn_sched_barrier(0);

    // ---- PV: P[16x64] @ V[64x128]; row-sum l via all-ones B-frag ----
    bf16x8 pf0 = *(const bf16x8*)&Pl[wave][lr][quad * 8];
    bf16x8 pf1 = *(const bf16x8*)&Pl[wave][lr][32 + quad * 8];
    __builtin_amdgcn_s_setprio(1);
    lacc = __builtin_amdgcn_mfma_f32_16x16x32_bf16(pf0, ones, lacc, 0, 0, 0);
    lacc = __builtin_amdgcn_mfma_f32_16x16x32_bf16(pf1, ones, lacc, 0, 0, 0);
    #pragma unroll
    for (int dc = 0; dc < 8; dc++) {
      oacc[dc] = __builtin_amdgcn_mfma_f32_16x16x32_bf16(pf0, vfr[dc][0], oacc[dc], 0, 0, 0);
      oacc[dc] = __builtin_amdgcn_mfma_f32_16x16x32_bf16(pf1, vfr[dc][1], oacc[dc], 0, 0, 0);
    }
    __builtin_amdgcn_s_setprio(0);

    // single barrier per tile: drains K prefetch (vmcnt) + WAR for next stage
    __syncthreads();
  }

  float inv[4];
  #pragma unroll
  for (int r = 0; r < 4; r++) inv[r] = 1.0f / lacc[r];
  bf16* aor = ao + ((size_t)(b * TT + q0 + quad * 4) * HH + h) * DD + lr;
  #pragma unroll
  for (int dc = 0; dc < 8; dc++)
    #pragma unroll
    for (int r = 0; r < 4; r++)
      aor[(size_t)r * HH * DD + dc * 16] = (bf16)(oacc[dc][r] * inv[r]);
}

// ---------------------------------------------------------------------------
// ws: Ab | Wt | qb | kb | vt | ao  (bf16, 32 MB each = 192 MB)
// ---------------------------------------------------------------------------
extern "C" void kernel_launch(void* const* d_in, const int* in_sizes, int n_in,
                              void* d_out, int out_size, void* d_ws, size_t ws_size,
                              hipStream_t stream)
{
  const float* hs   = (const float*)d_in[0];
  const float* sinp = (const float*)d_in[1];
  const float* cosp = (const float*)d_in[2];
  const float* Wq   = (const float*)d_in[4];
  const float* Wk   = (const float*)d_in[5];
  const float* Wv   = (const float*)d_in[6];
  const float* Wo   = (const float*)d_in[7];

  const size_t NE = (size_t)MM * CC;
  bf16* Ab = (bf16*)d_ws;
  bf16* Wt = Ab + NE;
  bf16* qb = Wt + NE;
  bf16* kb = qb + NE;
  bf16* vt = kb + NE;
  bf16* ao = vt + NE;

  dim3 gg(CC / 128, MM / 128), gb(256);
  dim3 gt(CC / 64, CC / 64);

  conv_k<<<NE / (256 * 8), 256, 0, stream>>>(hs, Ab);

  transpose_k<<<gt, gb, 0, stream>>>(Wq, Wt);
  gemm_k<0><<<gg, gb, 0, stream>>>(Ab, Wt, qb, sinp, cosp);

  transpose_k<<<gt, gb, 0, stream>>>(Wk, Wt);
  gemm_k<0><<<gg, gb, 0, stream>>>(Ab, Wt, kb, sinp, cosp);

  transpose_k<<<gt, gb, 0, stream>>>(Wv, Wt);
  gemm_k<1><<<gg, gb, 0, stream>>>(Ab, Wt, vt, sinp, cosp);

  attn_k<<<dim3(TT / 64, HH, BB), dim3(256), 0, stream>>>(qb, kb, vt, ao);

  transpose_k<<<gt, gb, 0, stream>>>(Wo, Wt);
  gemm_k<2><<<gg, gb, 0, stream>>>(ao, Wt, d_out, sinp, cosp);
}

// Round 3
// 1134.665 us; speedup vs baseline: 1.4229x; 1.4229x over previous
//
#include <hip/hip_runtime.h>
#include <hip/hip_bf16.h>
#include <cstdint>
#include <cstddef>

// Problem constants (B,T,C,H,D) = (2, 2048, 4096, 32, 128)
#define BB 2
#define TT 2048
#define CC 4096
#define HH 32
#define DD 128
#define MM (BB*TT)   // 4096 rows for all GEMMs

typedef __bf16 bf16;
typedef __bf16 bf16x8 __attribute__((ext_vector_type(8)));
typedef __bf16 bf16x4 __attribute__((ext_vector_type(4)));
typedef float  f32x4  __attribute__((ext_vector_type(4)));

__device__ __forceinline__ void async_copy16(const bf16* g, bf16* l) {
  __builtin_amdgcn_global_load_lds(
      (const __attribute__((address_space(1))) void*)g,
      (__attribute__((address_space(3))) void*)l, 16, 0, 0);
}

// ---------------------------------------------------------------------------
// fp32 -> bf16 convert (hidden_states).
// ---------------------------------------------------------------------------
__global__ __launch_bounds__(256) void conv_k(const float* __restrict__ X,
                                              bf16* __restrict__ Y)
{
  const size_t i = ((size_t)blockIdx.x * 256 + threadIdx.x) * 8;
  const float4 a = *(const float4*)(X + i);
  const float4 b = *(const float4*)(X + i + 4);
  bf16x8 w;
  w[0] = (bf16)a.x; w[1] = (bf16)a.y; w[2] = (bf16)a.z; w[3] = (bf16)a.w;
  w[4] = (bf16)b.x; w[5] = (bf16)b.y; w[6] = (bf16)b.z; w[7] = (bf16)b.w;
  *(bf16x8*)(Y + i) = w;
}

// ---------------------------------------------------------------------------
// W [K,N] fp32 -> Wt [N,K] bf16.  64x64 tile through LDS.
// ---------------------------------------------------------------------------
__global__ __launch_bounds__(256) void transpose_k(const float* __restrict__ W,
                                                   bf16* __restrict__ Wt)
{
  __shared__ bf16 Tl[64][72];
  const int tid = threadIdx.x;
  const int k0 = blockIdx.x * 64, n0 = blockIdx.y * 64;
  #pragma unroll
  for (int it = 0; it < 4; it++) {
    int idx = it * 256 + tid;          // 0..1023
    int kr  = idx >> 4;                // 0..63
    int nc  = (idx & 15) * 4;
    float4 v = *(const float4*)(W + (size_t)(k0 + kr) * CC + n0 + nc);
    Tl[nc + 0][kr] = (bf16)v.x;
    Tl[nc + 1][kr] = (bf16)v.y;
    Tl[nc + 2][kr] = (bf16)v.z;
    Tl[nc + 3][kr] = (bf16)v.w;
  }
  __syncthreads();
  #pragma unroll
  for (int it = 0; it < 2; it++) {
    int idx = it * 256 + tid;          // 0..511
    int nr  = idx >> 3;                // 0..63
    int kc  = (idx & 7) * 8;
    bf16x8 v = *(const bf16x8*)&Tl[nr][kc];
    *(bf16x8*)(Wt + (size_t)(n0 + nr) * CC + k0 + kc) = v;
  }
}

// ---------------------------------------------------------------------------
// GEMM v2: C[M=4096,N=4096] = A[M,K] @ Bt[N,K]^T, bf16, MFMA 16x16x32.
// 256x256 tile, BK=64, 8 waves (512 thr), per-wave 128x64 output.
// Counted-vmcnt pipeline (T3/T4): per K-tile, 4 quadrant phases (16 MFMA
// each) from buf[cur]; raw s_barrier; burst-stage tile t+2 into buf[cur];
// s_waitcnt vmcnt(8) (tile t+1 confirmed, t+2 in flight); s_barrier.
// Never drains vmcnt to 0 in the main loop.
// LDS XOR-swizzle (T2): slot ^= row&7 on 16B granules, via pre-swizzled
// global source (global_load_lds writes linearly) + swizzled ds_read addr.
// EPI: 0 = RoPE + bf16 [M,C]; 1 = bf16 transposed per head -> vt[B,H,D,T];
//      2 = fp32 [M,C] (final output)
// ---------------------------------------------------------------------------
template<int EPI>
__global__ __launch_bounds__(512, 2) void gemm_k(
    const bf16* __restrict__ A, const bf16* __restrict__ Bt,
    void* __restrict__ Out, const float* __restrict__ sinp,
    const float* __restrict__ cosp)
{
  constexpr int N = CC, K = CC;
  constexpr int NT = K / 64;           // 64 K-tiles
  __shared__ bf16 Al[2][256 * 64];     // 32 KB per buf
  __shared__ bf16 Bl[2][256 * 64];

  const int tid  = threadIdx.x;
  const int wave = tid >> 6, lane = tid & 63;
  const int lr   = lane & 15, quad = lane >> 4;
  const int m0   = blockIdx.y * 256, n0 = blockIdx.x * 256;
  const int wr   = wave >> 2, wc = wave & 3;   // 2 x 4 wave grid

  f32x4 acc[8][4];
  #pragma unroll
  for (int i = 0; i < 8; i++)
    #pragma unroll
    for (int j = 0; j < 4; j++) acc[i][j] = f32x4{0.f, 0.f, 0.f, 0.f};

  // staging: 8 loads/thread/tile.  load l of A: idx = l*512+tid;
  // row = idx>>3, slot = idx&7 (16B).  LDS dest linear (idx*16B);
  // source column pre-swizzled: col = (slot ^ (row&7))*8 elements.
  auto stage = [&](int buf, int t) {
    const int k0 = t * 64;
    #pragma unroll
    for (int l = 0; l < 4; l++) {
      const int idx = l * 512 + tid;
      const int row = idx >> 3, slot = idx & 7;
      const int col = (slot ^ (row & 7)) * 8;
      async_copy16(A + (size_t)(m0 + row) * K + k0 + col, &Al[buf][idx * 8]);
    }
    #pragma unroll
    for (int l = 0; l < 4; l++) {
      const int idx = l * 512 + tid;
      const int row = idx >> 3, slot = idx & 7;
      const int col = (slot ^ (row & 7)) * 8;
      async_copy16(Bt + (size_t)(n0 + row) * K + k0 + col, &Bl[buf][idx * 8]);
    }
  };

  // prologue: tiles 0,1 in flight; wait tile 0 only.
  stage(0, 0);
  stage(1, 1);
  asm volatile("s_waitcnt vmcnt(8)" ::: "memory");
  __builtin_amdgcn_s_barrier();
  __builtin_amdgcn_sched_barrier(0);

  for (int t = 0; t < NT; t++) {
    const int cur = t & 1;

    #pragma unroll
    for (int q = 0; q < 4; q++) {
      const int mh = q >> 1, nh = q & 1;
      bf16x8 af[4][2], bfr[2][2];
      #pragma unroll
      for (int i = 0; i < 4; i++) {
        const int rowl = wr * 128 + (mh * 4 + i) * 16 + lr;
        #pragma unroll
        for (int kh = 0; kh < 2; kh++) {
          const int c = kh * 4 + quad;
          af[i][kh] = *(const bf16x8*)&Al[cur][rowl * 64 + ((c ^ (rowl & 7)) * 8)];
        }
      }
      #pragma unroll
      for (int j = 0; j < 2; j++) {
        const int rowl = wc * 64 + (nh * 2 + j) * 16 + lr;
        #pragma unroll
        for (int kh = 0; kh < 2; kh++) {
          const int c = kh * 4 + quad;
          bfr[j][kh] = *(const bf16x8*)&Bl[cur][rowl * 64 + ((c ^ (rowl & 7)) * 8)];
        }
      }
      __builtin_amdgcn_s_setprio(1);
      #pragma unroll
      for (int i = 0; i < 4; i++)
        #pragma unroll
        for (int j = 0; j < 2; j++) {
          acc[mh*4+i][nh*2+j] = __builtin_amdgcn_mfma_f32_16x16x32_bf16(
              af[i][0], bfr[j][0], acc[mh*4+i][nh*2+j], 0, 0, 0);
          acc[mh*4+i][nh*2+j] = __builtin_amdgcn_mfma_f32_16x16x32_bf16(
              af[i][1], bfr[j][1], acc[mh*4+i][nh*2+j], 0, 0, 0);
        }
      __builtin_amdgcn_s_setprio(0);
    }

    // WAR: all reads of buf[cur] done before overwrite.
    __builtin_amdgcn_sched_barrier(0);
    __builtin_amdgcn_s_barrier();
    __builtin_amdgcn_sched_barrier(0);
    if (t + 2 < NT) {
      stage(cur, t + 2);
      asm volatile("s_waitcnt vmcnt(8)" ::: "memory");   // tile t+1 complete
    } else if (t + 1 < NT) {
      asm volatile("s_waitcnt vmcnt(0)" ::: "memory");   // tail
    }
    __builtin_amdgcn_s_barrier();        // t+1's data visible to all waves
    __builtin_amdgcn_sched_barrier(0);
  }

  // ---- epilogue: C/D layout col = lane&15, row = quad*4 + r ----
  #pragma unroll
  for (int mi = 0; mi < 8; mi++) {
    int grow = m0 + wr * 128 + mi * 16 + quad * 4;
    #pragma unroll
    for (int nj = 0; nj < 4; nj++) {
      int gc = n0 + wc * 64 + nj * 16 + lr;
      if (EPI == 0) {
        bf16* outp = (bf16*)Out;
        int dh = gc & (DD - 1);
        float sgn = (gc & 1) ? 1.0f : -1.0f;
        #pragma unroll
        for (int r = 0; r < 4; r++) {
          float x  = acc[mi][nj][r];
          float xp = __shfl_xor(x, 1, 64);
          int tq = (grow + r) & (TT - 1);
          float s = sinp[tq * DD + dh];
          float c = cosp[tq * DD + dh];
          outp[(size_t)(grow + r) * N + gc] = (bf16)(x * c + sgn * xp * s);
        }
      } else if (EPI == 1) {
        bf16* outp = (bf16*)Out;
        int hh = gc >> 7, dh = gc & (DD - 1);
        int bidx = grow >> 11, tq = grow & (TT - 1);
        bf16x4 w;
        #pragma unroll
        for (int r = 0; r < 4; r++) w[r] = (bf16)acc[mi][nj][r];
        *(bf16x4*)(outp + (((size_t)bidx * HH + hh) * DD + dh) * TT + tq) = w;
      } else {
        float* outp = (float*)Out;
        #pragma unroll
        for (int r = 0; r < 4; r++)
          outp[(size_t)(grow + r) * N + gc] = acc[mi][nj][r];
      }
    }
  }
}

// ---------------------------------------------------------------------------
// Flash attention v3 (round-1 version, 269 us): 4 waves/block, 64 q-rows/
// block (16 per wave), 64-key K/V tiles, DOUBLE-BUFFERED LDS via
// global_load_lds with prefetch-before-compute -> ONE __syncthreads/tile.
// Softmax: exp2-domain, lane-local deferred-max guard, row-sum via
// all-ones MFMA.  XOR-swizzled LDS (16B granule).
// ---------------------------------------------------------------------------
__global__ __launch_bounds__(256) void attn_k(
    const bf16* __restrict__ qb, const bf16* __restrict__ kb,
    const bf16* __restrict__ vt, bf16* __restrict__ ao)
{
  const int tid  = threadIdx.x;
  const int wave = tid >> 6, lane = tid & 63;
  const int lr   = lane & 15, quad = lane >> 4;
  const int qblk = blockIdx.x * 64;
  const int q0   = qblk + wave * 16;       // this wave's 16 q-rows
  const int h    = blockIdx.y, b = blockIdx.z;

  // Kl[sel] row k (256B): slot s (16B) holds K[k][(s ^ (k&15))*8 ..]
  // Vl[sel] row d (128B): slot s (16B) holds Vt[d][(s ^ (d&7))*8 ..]  (cols=t)
  __shared__ bf16 Kl[2][64 * 128];
  __shared__ bf16 Vl[2][128 * 64];
  __shared__ bf16 Pl[4][16][72];           // per-wave P (16B-aligned rows)

  // Q fragments (A-layout): lane holds Q[q0+lr][quad*8+j + 32*ds]
  bf16x8 qf[4];
  const bf16* qrow = qb + ((size_t)(b * TT + q0 + lr) * HH + h) * DD;
  #pragma unroll
  for (int ds = 0; ds < 4; ds++) qf[ds] = *(const bf16x8*)(qrow + ds * 32 + quad * 8);

  float m_r[4];
  f32x4 lacc;                              // row-sum accumulator (via ones-MFMA)
  f32x4 oacc[8];
  #pragma unroll
  for (int r = 0; r < 4; r++) { m_r[r] = -1e30f; lacc[r] = 0.f; }
  #pragma unroll
  for (int dc = 0; dc < 8; dc++) oacc[dc] = f32x4{0.f, 0.f, 0.f, 0.f};

  const int jt_end = blockIdx.x;           // inclusive (causal)
  const float sc2 = 0.12753861f;           // (1/sqrt(128)) * log2(e)

  const bf16* kbase = kb + ((size_t)(b * TT) * HH + h) * DD;
  const bf16* vbase = vt + ((size_t)b * HH + h) * DD * TT;

  // staging geometry (per wave, 4 instrs each for K and V):
  const int k_row_in = lane >> 4;          // 0..3   (4 rows of 256B per chunk)
  const int k_slot   = lane & 15;
  const int v_row_in = lane >> 3;          // 0..7   (8 rows of 128B per chunk)
  const int v_slot   = lane & 7;

  auto stage = [&](int sel, int jt) {
    const int k0 = jt * 64;
    #pragma unroll
    for (int s = 0; s < 4; s++) {
      const int ch   = s * 4 + wave;       // 0..15
      const int krow = ch * 4 + k_row_in;  // 0..63
      const int kcol = (k_slot ^ (krow & 15)) * 8;
      async_copy16(kbase + (size_t)(k0 + krow) * (HH * DD) + kcol,
                   &Kl[sel][ch * 512 + lane * 8]);
      const int drow = ch * 8 + v_row_in;  // 0..127
      const int vcol = (v_slot ^ (drow & 7)) * 8;
      async_copy16(vbase + (size_t)drow * TT + k0 + vcol,
                   &Vl[sel][ch * 512 + lane * 8]);
    }
  };

  bf16x8 ones;
  #pragma unroll
  for (int t = 0; t < 8; t++) ones[t] = (bf16)1.0f;

  // prologue: stage tile 0, drain.
  stage(0, 0);
  __syncthreads();

  for (int jt = 0; jt <= jt_end; jt++) {
    const int cur = jt & 1;
    if (jt < jt_end) stage(cur ^ 1, jt + 1);   // prefetch next tile (other buf)
    const int k0 = jt * 64;

    // ---- QK^T: 4 key groups of 16 ----
    f32x4 sacc[4];
    #pragma unroll
    for (int kk = 0; kk < 4; kk++) sacc[kk] = f32x4{0.f, 0.f, 0.f, 0.f};
    __builtin_amdgcn_s_setprio(1);
    #pragma unroll
    for (int ds = 0; ds < 4; ds++) {
      #pragma unroll
      for (int kk = 0; kk < 4; kk++) {
        const int key  = 16 * kk + lr;
        const int slot = (ds * 4 + quad) ^ lr;        // lr == key&15
        bf16x8 kf = *(const bf16x8*)&Kl[cur][key * 128 + slot * 8];
        sacc[kk] = __builtin_amdgcn_mfma_f32_16x16x32_bf16(qf[ds], kf, sacc[kk], 0, 0, 0);
      }
    }
    __builtin_amdgcn_s_setprio(0);

    // ---- softmax (raw-score domain; exp2 with folded scale) ----
    const int qr = q0 + quad * 4;
    float v[4][4], lmx[4];
    if (jt == jt_end) {                    // only the diagonal tile masks
      #pragma unroll
      for (int r = 0; r < 4; r++)
        #pragma unroll
        for (int kk = 0; kk < 4; kk++) {
          float x = sacc[kk][r];
          if (k0 + 16 * kk + lr > qr + r) x = -1e30f;
          v[r][kk] = x;
        }
    } else {
      #pragma unroll
      for (int r = 0; r < 4; r++)
        #pragma unroll
        for (int kk = 0; kk < 4; kk++) v[r][kk] = sacc[kk][r];
    }
    bool need = false;
    #pragma unroll
    for (int r = 0; r < 4; r++) {
      lmx[r] = fmaxf(fmaxf(v[r][0], v[r][1]), fmaxf(v[r][2], v[r][3]));
      need = need || (lmx[r] > m_r[r] + 24.0f);   // e bounded by 2^(24*sc2)≈8.4
    }
    if (__any(need)) {                     // rare: full reduce + rescale
      #pragma unroll
      for (int r = 0; r < 4; r++) {
        float mx = lmx[r];
        #pragma unroll
        for (int off = 1; off < 16; off <<= 1) mx = fmaxf(mx, __shfl_xor(mx, off, 64));
        float mn = fmaxf(m_r[r], mx);
        float al = __builtin_amdgcn_exp2f((m_r[r] - mn) * sc2);
        lacc[r] *= al;
        #pragma unroll
        for (int dc = 0; dc < 8; dc++) oacc[dc][r] *= al;
        m_r[r] = mn;
      }
    }
    #pragma unroll
    for (int r = 0; r < 4; r++) {
      const float mb = m_r[r] * sc2;
      #pragma unroll
      for (int kk = 0; kk < 4; kk++) {
        float e = __builtin_amdgcn_exp2f(__builtin_fmaf(v[r][kk], sc2, -mb));
        Pl[wave][quad * 4 + r][kk * 16 + lr] = (bf16)e;
      }
    }

    // wave-private P: only in-wave DS ordering needed (no block barrier)
    asm volatile("s_waitcnt lgkmcnt(0)" ::: "memory");
    __builtin_amdgcn_sched_barrier(0);

    // ---- PV: P[16x64] @ V[64x128]; row-sum l via all-ones B-frag ----
    bf16x8 pf0 = *(const bf16x8*)&Pl[wave][lr][quad * 8];
    bf16x8 pf1 = *(const bf16x8*)&Pl[wave][lr][32 + quad * 8];
    __builtin_amdgcn_s_setprio(1);
    lacc = __builtin_amdgcn_mfma_f32_16x16x32_bf16(pf0, ones, lacc, 0, 0, 0);
    lacc = __builtin_amdgcn_mfma_f32_16x16x32_bf16(pf1, ones, lacc, 0, 0, 0);
    #pragma unroll
    for (int dc = 0; dc < 8; dc++) {
      const int d  = dc * 16 + lr;
      const int s0 = (quad)     ^ (lr & 7);
      const int s1 = (4 + quad) ^ (lr & 7);
      bf16x8 vf0 = *(const bf16x8*)&Vl[cur][d * 64 + s0 * 8];
      bf16x8 vf1 = *(const bf16x8*)&Vl[cur][d * 64 + s1 * 8];
      oacc[dc] = __builtin_amdgcn_mfma_f32_16x16x32_bf16(pf0, vf0, oacc[dc], 0, 0, 0);
      oacc[dc] = __builtin_amdgcn_mfma_f32_16x16x32_bf16(pf1, vf1, oacc[dc], 0, 0, 0);
    }
    __builtin_amdgcn_s_setprio(0);

    // single barrier per tile: drains prefetch (vmcnt) + WAR for next stage
    __syncthreads();
  }

  float inv[4];
  #pragma unroll
  for (int r = 0; r < 4; r++) inv[r] = 1.0f / lacc[r];
  bf16* aor = ao + ((size_t)(b * TT + q0 + quad * 4) * HH + h) * DD + lr;
  #pragma unroll
  for (int dc = 0; dc < 8; dc++)
    #pragma unroll
    for (int r = 0; r < 4; r++)
      aor[(size_t)r * HH * DD + dc * 16] = (bf16)(oacc[dc][r] * inv[r]);
}

// ---------------------------------------------------------------------------
// ws: Ab | Wt | qb | kb | vt | ao  (bf16, 32 MB each = 192 MB)
// ---------------------------------------------------------------------------
extern "C" void kernel_launch(void* const* d_in, const int* in_sizes, int n_in,
                              void* d_out, int out_size, void* d_ws, size_t ws_size,
                              hipStream_t stream)
{
  const float* hs   = (const float*)d_in[0];
  const float* sinp = (const float*)d_in[1];
  const float* cosp = (const float*)d_in[2];
  const float* Wq   = (const float*)d_in[4];
  const float* Wk   = (const float*)d_in[5];
  const float* Wv   = (const float*)d_in[6];
  const float* Wo   = (const float*)d_in[7];

  const size_t NE = (size_t)MM * CC;
  bf16* Ab = (bf16*)d_ws;
  bf16* Wt = Ab + NE;
  bf16* qb = Wt + NE;
  bf16* kb = qb + NE;
  bf16* vt = kb + NE;
  bf16* ao = vt + NE;

  dim3 gg(CC / 256, MM / 256), gb(512);
  dim3 gt(CC / 64, CC / 64);

  conv_k<<<NE / (256 * 8), 256, 0, stream>>>(hs, Ab);

  transpose_k<<<gt, dim3(256), 0, stream>>>(Wq, Wt);
  gemm_k<0><<<gg, gb, 0, stream>>>(Ab, Wt, qb, sinp, cosp);

  transpose_k<<<gt, dim3(256), 0, stream>>>(Wk, Wt);
  gemm_k<0><<<gg, gb, 0, stream>>>(Ab, Wt, kb, sinp, cosp);

  transpose_k<<<gt, dim3(256), 0, stream>>>(Wv, Wt);
  gemm_k<1><<<gg, gb, 0, stream>>>(Ab, Wt, vt, sinp, cosp);

  attn_k<<<dim3(TT / 64, HH, BB), dim3(256), 0, stream>>>(qb, kb, vt, ao);

  transpose_k<<<gt, dim3(256), 0, stream>>>(Wo, Wt);
  gemm_k<2><<<gg, gb, 0, stream>>>(ao, Wt, d_out, sinp, cosp);
}

// Round 4
// 1054.294 us; speedup vs baseline: 1.5314x; 1.0762x over previous
//
#include <hip/hip_runtime.h>
#include <hip/hip_bf16.h>
#include <cstdint>
#include <cstddef>

// Problem constants (B,T,C,H,D) = (2, 2048, 4096, 32, 128)
#define BB 2
#define TT 2048
#define CC 4096
#define HH 32
#define DD 128
#define MM (BB*TT)   // 4096 rows for all GEMMs

typedef __bf16 bf16;
typedef __bf16 bf16x8 __attribute__((ext_vector_type(8)));
typedef __bf16 bf16x4 __attribute__((ext_vector_type(4)));
typedef float  f32x4  __attribute__((ext_vector_type(4)));

__device__ __forceinline__ void async_copy16(const bf16* g, bf16* l) {
  __builtin_amdgcn_global_load_lds(
      (const __attribute__((address_space(1))) void*)g,
      (__attribute__((address_space(3))) void*)l, 16, 0, 0);
}

// ---------------------------------------------------------------------------
// fp32 -> bf16 convert (hidden_states).
// ---------------------------------------------------------------------------
__global__ __launch_bounds__(256) void conv_k(const float* __restrict__ X,
                                              bf16* __restrict__ Y)
{
  const size_t i = ((size_t)blockIdx.x * 256 + threadIdx.x) * 8;
  const float4 a = *(const float4*)(X + i);
  const float4 b = *(const float4*)(X + i + 4);
  bf16x8 w;
  w[0] = (bf16)a.x; w[1] = (bf16)a.y; w[2] = (bf16)a.z; w[3] = (bf16)a.w;
  w[4] = (bf16)b.x; w[5] = (bf16)b.y; w[6] = (bf16)b.z; w[7] = (bf16)b.w;
  *(bf16x8*)(Y + i) = w;
}

// ---------------------------------------------------------------------------
// W [K,N] fp32 -> Wt [N,K] bf16.  64x64 tile through LDS.
// ---------------------------------------------------------------------------
__global__ __launch_bounds__(256) void transpose_k(const float* __restrict__ W,
                                                   bf16* __restrict__ Wt)
{
  __shared__ bf16 Tl[64][72];
  const int tid = threadIdx.x;
  const int k0 = blockIdx.x * 64, n0 = blockIdx.y * 64;
  #pragma unroll
  for (int it = 0; it < 4; it++) {
    int idx = it * 256 + tid;          // 0..1023
    int kr  = idx >> 4;                // 0..63
    int nc  = (idx & 15) * 4;
    float4 v = *(const float4*)(W + (size_t)(k0 + kr) * CC + n0 + nc);
    Tl[nc + 0][kr] = (bf16)v.x;
    Tl[nc + 1][kr] = (bf16)v.y;
    Tl[nc + 2][kr] = (bf16)v.z;
    Tl[nc + 3][kr] = (bf16)v.w;
  }
  __syncthreads();
  #pragma unroll
  for (int it = 0; it < 2; it++) {
    int idx = it * 256 + tid;          // 0..511
    int nr  = idx >> 3;                // 0..63
    int kc  = (idx & 7) * 8;
    bf16x8 v = *(const bf16x8*)&Tl[nr][kc];
    *(bf16x8*)(Wt + (size_t)(n0 + nr) * CC + k0 + kc) = v;
  }
}

// ---------------------------------------------------------------------------
// GEMM v3: C[M=4096,N=4096] = A[M,K] @ Bt[N,K]^T, bf16, MFMA 16x16x32.
// 256x256 tile, BK=64, 8 waves (512 thr), per-wave 128x64 output.
// Consume-early schedule: per K-tile, (1) ds_read the wave's FULL A/B
// fragments to registers (24 x ds_read_b128), (2) lgkmcnt(0)+barrier ->
// buf[cur] free, (3) stage tile t+2 into buf[cur] + vmcnt(8) (t+1's own
// loads confirmed; collective guarantee via end barrier), (4) 64 MFMA
// pure-register, overlapping the in-flight t+2 loads, (5) barrier.
// vmcnt never drained to 0 in the main loop (T4).
// LDS XOR-swizzle (T2): 16B slot ^= row&7, via pre-swizzled global source
// (global_load_lds writes linearly) + swizzled ds_read addr (rule #21).
// EPI: 0 = RoPE + bf16 [M,C]; 1 = bf16 transposed per head -> vt[B,H,D,T];
//      2 = fp32 [M,C] (final output)
// ---------------------------------------------------------------------------
template<int EPI>
__global__ __launch_bounds__(512, 2) void gemm_k(
    const bf16* __restrict__ A, const bf16* __restrict__ Bt,
    void* __restrict__ Out, const float* __restrict__ sinp,
    const float* __restrict__ cosp)
{
  constexpr int N = CC, K = CC;
  constexpr int NT = K / 64;           // 64 K-tiles
  __shared__ bf16 Al[2][256 * 64];     // 32 KB per buf
  __shared__ bf16 Bl[2][256 * 64];

  const int tid  = threadIdx.x;
  const int wave = tid >> 6, lane = tid & 63;
  const int lr   = lane & 15, quad = lane >> 4;
  const int m0   = blockIdx.y * 256, n0 = blockIdx.x * 256;
  const int wr   = wave >> 2, wc = wave & 3;   // 2 x 4 wave grid

  f32x4 acc[8][4];
  #pragma unroll
  for (int i = 0; i < 8; i++)
    #pragma unroll
    for (int j = 0; j < 4; j++) acc[i][j] = f32x4{0.f, 0.f, 0.f, 0.f};

  // staging: 8 loads/thread/tile.  load l of A: idx = l*512+tid;
  // row = idx>>3, slot = idx&7 (16B).  LDS dest linear (idx*16B);
  // source column pre-swizzled: col = (slot ^ (row&7))*8 elements.
  auto stage = [&](int buf, int t) {
    const int k0 = t * 64;
    #pragma unroll
    for (int l = 0; l < 4; l++) {
      const int idx = l * 512 + tid;
      const int row = idx >> 3, slot = idx & 7;
      const int col = (slot ^ (row & 7)) * 8;
      async_copy16(A + (size_t)(m0 + row) * K + k0 + col, &Al[buf][idx * 8]);
    }
    #pragma unroll
    for (int l = 0; l < 4; l++) {
      const int idx = l * 512 + tid;
      const int row = idx >> 3, slot = idx & 7;
      const int col = (slot ^ (row & 7)) * 8;
      async_copy16(Bt + (size_t)(n0 + row) * K + k0 + col, &Bl[buf][idx * 8]);
    }
  };

  // prologue: tiles 0,1 in flight; wait tile 0 only.
  stage(0, 0);
  stage(1, 1);
  asm volatile("s_waitcnt vmcnt(8)" ::: "memory");
  __builtin_amdgcn_s_barrier();
  __builtin_amdgcn_sched_barrier(0);

  for (int t = 0; t < NT; t++) {
    const int cur = t & 1;

    // ---- (1) consume buf[cur] fully into registers ----
    bf16x8 af[8][2], bfr[4][2];
    #pragma unroll
    for (int i = 0; i < 8; i++) {
      const int rowl = wr * 128 + i * 16 + lr;
      #pragma unroll
      for (int kh = 0; kh < 2; kh++) {
        const int c = kh * 4 + quad;
        af[i][kh] = *(const bf16x8*)&Al[cur][rowl * 64 + ((c ^ (rowl & 7)) * 8)];
      }
    }
    #pragma unroll
    for (int j = 0; j < 4; j++) {
      const int rowl = wc * 64 + j * 16 + lr;
      #pragma unroll
      for (int kh = 0; kh < 2; kh++) {
        const int c = kh * 4 + quad;
        bfr[j][kh] = *(const bf16x8*)&Bl[cur][rowl * 64 + ((c ^ (rowl & 7)) * 8)];
      }
    }
    // reads DONE (not just issued) before anyone may overwrite buf[cur]
    asm volatile("s_waitcnt lgkmcnt(0)" ::: "memory");
    __builtin_amdgcn_sched_barrier(0);
    __builtin_amdgcn_s_barrier();
    __builtin_amdgcn_sched_barrier(0);

    // ---- (2) stage t+2 into the just-freed buf; confirm own t+1 loads ----
    if (t + 2 < NT) {
      stage(cur, t + 2);
      asm volatile("s_waitcnt vmcnt(8)" ::: "memory");   // t+1 (own) landed
    } else if (t + 1 < NT) {
      asm volatile("s_waitcnt vmcnt(0)" ::: "memory");   // tail
    }
    __builtin_amdgcn_sched_barrier(0);

    // ---- (3) 64 MFMA pure-register; t+2 loads fly underneath ----
    __builtin_amdgcn_s_setprio(1);
    #pragma unroll
    for (int kh = 0; kh < 2; kh++)
      #pragma unroll
      for (int i = 0; i < 8; i++)
        #pragma unroll
        for (int j = 0; j < 4; j++)
          acc[i][j] = __builtin_amdgcn_mfma_f32_16x16x32_bf16(
              af[i][kh], bfr[j][kh], acc[i][j], 0, 0, 0);
    __builtin_amdgcn_s_setprio(0);

    // ---- (4) end barrier: every wave passed its vmcnt -> t+1 visible ----
    __builtin_amdgcn_sched_barrier(0);
    __builtin_amdgcn_s_barrier();
    __builtin_amdgcn_sched_barrier(0);
  }

  // ---- epilogue: C/D layout col = lane&15, row = quad*4 + r ----
  #pragma unroll
  for (int mi = 0; mi < 8; mi++) {
    int grow = m0 + wr * 128 + mi * 16 + quad * 4;
    #pragma unroll
    for (int nj = 0; nj < 4; nj++) {
      int gc = n0 + wc * 64 + nj * 16 + lr;
      if (EPI == 0) {
        bf16* outp = (bf16*)Out;
        int dh = gc & (DD - 1);
        float sgn = (gc & 1) ? 1.0f : -1.0f;
        #pragma unroll
        for (int r = 0; r < 4; r++) {
          float x  = acc[mi][nj][r];
          float xp = __shfl_xor(x, 1, 64);
          int tq = (grow + r) & (TT - 1);
          float s = sinp[tq * DD + dh];
          float c = cosp[tq * DD + dh];
          outp[(size_t)(grow + r) * N + gc] = (bf16)(x * c + sgn * xp * s);
        }
      } else if (EPI == 1) {
        bf16* outp = (bf16*)Out;
        int hh = gc >> 7, dh = gc & (DD - 1);
        int bidx = grow >> 11, tq = grow & (TT - 1);
        bf16x4 w;
        #pragma unroll
        for (int r = 0; r < 4; r++) w[r] = (bf16)acc[mi][nj][r];
        *(bf16x4*)(outp + (((size_t)bidx * HH + hh) * DD + dh) * TT + tq) = w;
      } else {
        float* outp = (float*)Out;
        #pragma unroll
        for (int r = 0; r < 4; r++)
          outp[(size_t)(grow + r) * N + gc] = acc[mi][nj][r];
      }
    }
  }
}

// ---------------------------------------------------------------------------
// Flash attention v3 (round-1 version, 269 us): 4 waves/block, 64 q-rows/
// block (16 per wave), 64-key K/V tiles, DOUBLE-BUFFERED LDS via
// global_load_lds with prefetch-before-compute -> ONE __syncthreads/tile.
// Softmax: exp2-domain, lane-local deferred-max guard, row-sum via
// all-ones MFMA.  XOR-swizzled LDS (16B granule).
// ---------------------------------------------------------------------------
__global__ __launch_bounds__(256) void attn_k(
    const bf16* __restrict__ qb, const bf16* __restrict__ kb,
    const bf16* __restrict__ vt, bf16* __restrict__ ao)
{
  const int tid  = threadIdx.x;
  const int wave = tid >> 6, lane = tid & 63;
  const int lr   = lane & 15, quad = lane >> 4;
  const int qblk = blockIdx.x * 64;
  const int q0   = qblk + wave * 16;       // this wave's 16 q-rows
  const int h    = blockIdx.y, b = blockIdx.z;

  // Kl[sel] row k (256B): slot s (16B) holds K[k][(s ^ (k&15))*8 ..]
  // Vl[sel] row d (128B): slot s (16B) holds Vt[d][(s ^ (d&7))*8 ..]  (cols=t)
  __shared__ bf16 Kl[2][64 * 128];
  __shared__ bf16 Vl[2][128 * 64];
  __shared__ bf16 Pl[4][16][72];           // per-wave P (16B-aligned rows)

  // Q fragments (A-layout): lane holds Q[q0+lr][quad*8+j + 32*ds]
  bf16x8 qf[4];
  const bf16* qrow = qb + ((size_t)(b * TT + q0 + lr) * HH + h) * DD;
  #pragma unroll
  for (int ds = 0; ds < 4; ds++) qf[ds] = *(const bf16x8*)(qrow + ds * 32 + quad * 8);

  float m_r[4];
  f32x4 lacc;                              // row-sum accumulator (via ones-MFMA)
  f32x4 oacc[8];
  #pragma unroll
  for (int r = 0; r < 4; r++) { m_r[r] = -1e30f; lacc[r] = 0.f; }
  #pragma unroll
  for (int dc = 0; dc < 8; dc++) oacc[dc] = f32x4{0.f, 0.f, 0.f, 0.f};

  const int jt_end = blockIdx.x;           // inclusive (causal)
  const float sc2 = 0.12753861f;           // (1/sqrt(128)) * log2(e)

  const bf16* kbase = kb + ((size_t)(b * TT) * HH + h) * DD;
  const bf16* vbase = vt + ((size_t)b * HH + h) * DD * TT;

  // staging geometry (per wave, 4 instrs each for K and V):
  const int k_row_in = lane >> 4;          // 0..3   (4 rows of 256B per chunk)
  const int k_slot   = lane & 15;
  const int v_row_in = lane >> 3;          // 0..7   (8 rows of 128B per chunk)
  const int v_slot   = lane & 7;

  auto stage = [&](int sel, int jt) {
    const int k0 = jt * 64;
    #pragma unroll
    for (int s = 0; s < 4; s++) {
      const int ch   = s * 4 + wave;       // 0..15
      const int krow = ch * 4 + k_row_in;  // 0..63
      const int kcol = (k_slot ^ (krow & 15)) * 8;
      async_copy16(kbase + (size_t)(k0 + krow) * (HH * DD) + kcol,
                   &Kl[sel][ch * 512 + lane * 8]);
      const int drow = ch * 8 + v_row_in;  // 0..127
      const int vcol = (v_slot ^ (drow & 7)) * 8;
      async_copy16(vbase + (size_t)drow * TT + k0 + vcol,
                   &Vl[sel][ch * 512 + lane * 8]);
    }
  };

  bf16x8 ones;
  #pragma unroll
  for (int t = 0; t < 8; t++) ones[t] = (bf16)1.0f;

  // prologue: stage tile 0, drain.
  stage(0, 0);
  __syncthreads();

  for (int jt = 0; jt <= jt_end; jt++) {
    const int cur = jt & 1;
    if (jt < jt_end) stage(cur ^ 1, jt + 1);   // prefetch next tile (other buf)
    const int k0 = jt * 64;

    // ---- QK^T: 4 key groups of 16 ----
    f32x4 sacc[4];
    #pragma unroll
    for (int kk = 0; kk < 4; kk++) sacc[kk] = f32x4{0.f, 0.f, 0.f, 0.f};
    __builtin_amdgcn_s_setprio(1);
    #pragma unroll
    for (int ds = 0; ds < 4; ds++) {
      #pragma unroll
      for (int kk = 0; kk < 4; kk++) {
        const int key  = 16 * kk + lr;
        const int slot = (ds * 4 + quad) ^ lr;        // lr == key&15
        bf16x8 kf = *(const bf16x8*)&Kl[cur][key * 128 + slot * 8];
        sacc[kk] = __builtin_amdgcn_mfma_f32_16x16x32_bf16(qf[ds], kf, sacc[kk], 0, 0, 0);
      }
    }
    __builtin_amdgcn_s_setprio(0);

    // ---- softmax (raw-score domain; exp2 with folded scale) ----
    const int qr = q0 + quad * 4;
    float v[4][4], lmx[4];
    if (jt == jt_end) {                    // only the diagonal tile masks
      #pragma unroll
      for (int r = 0; r < 4; r++)
        #pragma unroll
        for (int kk = 0; kk < 4; kk++) {
          float x = sacc[kk][r];
          if (k0 + 16 * kk + lr > qr + r) x = -1e30f;
          v[r][kk] = x;
        }
    } else {
      #pragma unroll
      for (int r = 0; r < 4; r++)
        #pragma unroll
        for (int kk = 0; kk < 4; kk++) v[r][kk] = sacc[kk][r];
    }
    bool need = false;
    #pragma unroll
    for (int r = 0; r < 4; r++) {
      lmx[r] = fmaxf(fmaxf(v[r][0], v[r][1]), fmaxf(v[r][2], v[r][3]));
      need = need || (lmx[r] > m_r[r] + 24.0f);   // e bounded by 2^(24*sc2)≈8.4
    }
    if (__any(need)) {                     // rare: full reduce + rescale
      #pragma unroll
      for (int r = 0; r < 4; r++) {
        float mx = lmx[r];
        #pragma unroll
        for (int off = 1; off < 16; off <<= 1) mx = fmaxf(mx, __shfl_xor(mx, off, 64));
        float mn = fmaxf(m_r[r], mx);
        float al = __builtin_amdgcn_exp2f((m_r[r] - mn) * sc2);
        lacc[r] *= al;
        #pragma unroll
        for (int dc = 0; dc < 8; dc++) oacc[dc][r] *= al;
        m_r[r] = mn;
      }
    }
    #pragma unroll
    for (int r = 0; r < 4; r++) {
      const float mb = m_r[r] * sc2;
      #pragma unroll
      for (int kk = 0; kk < 4; kk++) {
        float e = __builtin_amdgcn_exp2f(__builtin_fmaf(v[r][kk], sc2, -mb));
        Pl[wave][quad * 4 + r][kk * 16 + lr] = (bf16)e;
      }
    }

    // wave-private P: only in-wave DS ordering needed (no block barrier)
    asm volatile("s_waitcnt lgkmcnt(0)" ::: "memory");
    __builtin_amdgcn_sched_barrier(0);

    // ---- PV: P[16x64] @ V[64x128]; row-sum l via all-ones B-frag ----
    bf16x8 pf0 = *(const bf16x8*)&Pl[wave][lr][quad * 8];
    bf16x8 pf1 = *(const bf16x8*)&Pl[wave][lr][32 + quad * 8];
    __builtin_amdgcn_s_setprio(1);
    lacc = __builtin_amdgcn_mfma_f32_16x16x32_bf16(pf0, ones, lacc, 0, 0, 0);
    lacc = __builtin_amdgcn_mfma_f32_16x16x32_bf16(pf1, ones, lacc, 0, 0, 0);
    #pragma unroll
    for (int dc = 0; dc < 8; dc++) {
      const int d  = dc * 16 + lr;
      const int s0 = (quad)     ^ (lr & 7);
      const int s1 = (4 + quad) ^ (lr & 7);
      bf16x8 vf0 = *(const bf16x8*)&Vl[cur][d * 64 + s0 * 8];
      bf16x8 vf1 = *(const bf16x8*)&Vl[cur][d * 64 + s1 * 8];
      oacc[dc] = __builtin_amdgcn_mfma_f32_16x16x32_bf16(pf0, vf0, oacc[dc], 0, 0, 0);
      oacc[dc] = __builtin_amdgcn_mfma_f32_16x16x32_bf16(pf1, vf1, oacc[dc], 0, 0, 0);
    }
    __builtin_amdgcn_s_setprio(0);

    // single barrier per tile: drains prefetch (vmcnt) + WAR for next stage
    __syncthreads();
  }

  float inv[4];
  #pragma unroll
  for (int r = 0; r < 4; r++) inv[r] = 1.0f / lacc[r];
  bf16* aor = ao + ((size_t)(b * TT + q0 + quad * 4) * HH + h) * DD + lr;
  #pragma unroll
  for (int dc = 0; dc < 8; dc++)
    #pragma unroll
    for (int r = 0; r < 4; r++)
      aor[(size_t)r * HH * DD + dc * 16] = (bf16)(oacc[dc][r] * inv[r]);
}

// ---------------------------------------------------------------------------
// ws: Ab | Wt | qb | kb | vt | ao  (bf16, 32 MB each = 192 MB)
// ---------------------------------------------------------------------------
extern "C" void kernel_launch(void* const* d_in, const int* in_sizes, int n_in,
                              void* d_out, int out_size, void* d_ws, size_t ws_size,
                              hipStream_t stream)
{
  const float* hs   = (const float*)d_in[0];
  const float* sinp = (const float*)d_in[1];
  const float* cosp = (const float*)d_in[2];
  const float* Wq   = (const float*)d_in[4];
  const float* Wk   = (const float*)d_in[5];
  const float* Wv   = (const float*)d_in[6];
  const float* Wo   = (const float*)d_in[7];

  const size_t NE = (size_t)MM * CC;
  bf16* Ab = (bf16*)d_ws;
  bf16* Wt = Ab + NE;
  bf16* qb = Wt + NE;
  bf16* kb = qb + NE;
  bf16* vt = kb + NE;
  bf16* ao = vt + NE;

  dim3 gg(CC / 256, MM / 256), gb(512);
  dim3 gt(CC / 64, CC / 64);

  conv_k<<<NE / (256 * 8), 256, 0, stream>>>(hs, Ab);

  transpose_k<<<gt, dim3(256), 0, stream>>>(Wq, Wt);
  gemm_k<0><<<gg, gb, 0, stream>>>(Ab, Wt, qb, sinp, cosp);

  transpose_k<<<gt, dim3(256), 0, stream>>>(Wk, Wt);
  gemm_k<0><<<gg, gb, 0, stream>>>(Ab, Wt, kb, sinp, cosp);

  transpose_k<<<gt, dim3(256), 0, stream>>>(Wv, Wt);
  gemm_k<1><<<gg, gb, 0, stream>>>(Ab, Wt, vt, sinp, cosp);

  attn_k<<<dim3(TT / 64, HH, BB), dim3(256), 0, stream>>>(qb, kb, vt, ao);

  transpose_k<<<gt, dim3(256), 0, stream>>>(Wo, Wt);
  gemm_k<2><<<gg, gb, 0, stream>>>(ao, Wt, d_out, sinp, cosp);
}

// Round 5
// 1015.497 us; speedup vs baseline: 1.5899x; 1.0382x over previous
//
#include <hip/hip_runtime.h>
#include <hip/hip_bf16.h>
#include <cstdint>
#include <cstddef>

// Problem constants (B,T,C,H,D) = (2, 2048, 4096, 32, 128)
#define BB 2
#define TT 2048
#define CC 4096
#define HH 32
#define DD 128
#define MM (BB*TT)   // 4096 rows for all GEMMs

typedef __bf16 bf16;
typedef __bf16 bf16x8 __attribute__((ext_vector_type(8)));
typedef __bf16 bf16x4 __attribute__((ext_vector_type(4)));
typedef float  f32x4  __attribute__((ext_vector_type(4)));

__device__ __forceinline__ void async_copy16(const bf16* g, bf16* l) {
  __builtin_amdgcn_global_load_lds(
      (const __attribute__((address_space(1))) void*)g,
      (__attribute__((address_space(3))) void*)l, 16, 0, 0);
}

// ---------------------------------------------------------------------------
// fp32 -> bf16 convert (hidden_states).
// ---------------------------------------------------------------------------
__global__ __launch_bounds__(256) void conv_k(const float* __restrict__ X,
                                              bf16* __restrict__ Y)
{
  const size_t i = ((size_t)blockIdx.x * 256 + threadIdx.x) * 8;
  const float4 a = *(const float4*)(X + i);
  const float4 b = *(const float4*)(X + i + 4);
  bf16x8 w;
  w[0] = (bf16)a.x; w[1] = (bf16)a.y; w[2] = (bf16)a.z; w[3] = (bf16)a.w;
  w[4] = (bf16)b.x; w[5] = (bf16)b.y; w[6] = (bf16)b.z; w[7] = (bf16)b.w;
  *(bf16x8*)(Y + i) = w;
}

// ---------------------------------------------------------------------------
// W [K,N] fp32 -> Wt [N,K] bf16.  64x64 tile through LDS.
// ---------------------------------------------------------------------------
__global__ __launch_bounds__(256) void transpose_k(const float* __restrict__ W,
                                                   bf16* __restrict__ Wt)
{
  __shared__ bf16 Tl[64][72];
  const int tid = threadIdx.x;
  const int k0 = blockIdx.x * 64, n0 = blockIdx.y * 64;
  #pragma unroll
  for (int it = 0; it < 4; it++) {
    int idx = it * 256 + tid;          // 0..1023
    int kr  = idx >> 4;                // 0..63
    int nc  = (idx & 15) * 4;
    float4 v = *(const float4*)(W + (size_t)(k0 + kr) * CC + n0 + nc);
    Tl[nc + 0][kr] = (bf16)v.x;
    Tl[nc + 1][kr] = (bf16)v.y;
    Tl[nc + 2][kr] = (bf16)v.z;
    Tl[nc + 3][kr] = (bf16)v.w;
  }
  __syncthreads();
  #pragma unroll
  for (int it = 0; it < 2; it++) {
    int idx = it * 256 + tid;          // 0..511
    int nr  = idx >> 3;                // 0..63
    int kc  = (idx & 7) * 8;
    bf16x8 v = *(const bf16x8*)&Tl[nr][kc];
    *(bf16x8*)(Wt + (size_t)(n0 + nr) * CC + k0 + kc) = v;
  }
}

// ---------------------------------------------------------------------------
// GEMM v4: C[M=4096,N=4096] = A[M,K] @ Bt[N,K]^T, bf16, MFMA 16x16x32.
// 256x256 tile, BK=64, 8 waves (512 thr), per-wave 128x64 output.
// Overlap schedule: per K-tile, (1) issue all 24 ds_read_b128, (2) run all
// 64 MFMAs -- compiler interleaves fine-grained lgkmcnt waits, so the
// ~2300-cyc LDS read stream overlaps the ~2480-cyc MFMA stream (they were
// serialized in v3 -> this is the fix), (3) lgkmcnt(0)+barrier (WAR, no-op
// wait by then), (4) stage tile t+2 + vmcnt(8) (t+1 landed a tile ago),
// (5) barrier.  vmcnt never drained to 0 in the main loop (T4).
// T1: XCD-aware block swizzle -- each XCD's 32 co-resident blocks form 2
// full A-panel rows, so A is served from the XCD's own L2.
// LDS XOR-swizzle (T2): 16B slot ^= row&7, via pre-swizzled global source
// (global_load_lds writes linearly) + swizzled ds_read addr (rule #21).
// EPI: 0 = RoPE + bf16 [M,C]; 1 = bf16 transposed per head -> vt[B,H,D,T];
//      2 = fp32 [M,C] (final output)
// ---------------------------------------------------------------------------
template<int EPI>
__global__ __launch_bounds__(512, 2) void gemm_k(
    const bf16* __restrict__ A, const bf16* __restrict__ Bt,
    void* __restrict__ Out, const float* __restrict__ sinp,
    const float* __restrict__ cosp)
{
  constexpr int N = CC, K = CC;
  constexpr int NT = K / 64;           // 64 K-tiles
  __shared__ bf16 Al[2][256 * 64];     // 32 KB per buf
  __shared__ bf16 Bl[2][256 * 64];

  const int tid  = threadIdx.x;
  const int wave = tid >> 6, lane = tid & 63;
  const int lr   = lane & 15, quad = lane >> 4;

  // T1 XCD swizzle: dispatch d -> XCD d%8 (round-robin).  Remap so XCD g
  // computes contiguous tile ids g*32..g*32+31 (= 2 full by-rows).
  const int dflat = blockIdx.y * 16 + blockIdx.x;      // 256 blocks
  const int tile  = (dflat & 7) * 32 + (dflat >> 3);
  const int m0    = (tile >> 4) * 256, n0 = (tile & 15) * 256;

  const int wr   = wave >> 2, wc = wave & 3;   // 2 x 4 wave grid

  f32x4 acc[8][4];
  #pragma unroll
  for (int i = 0; i < 8; i++)
    #pragma unroll
    for (int j = 0; j < 4; j++) acc[i][j] = f32x4{0.f, 0.f, 0.f, 0.f};

  // staging: 8 loads/thread/tile.  load l of A: idx = l*512+tid;
  // row = idx>>3, slot = idx&7 (16B).  LDS dest linear (idx*16B);
  // source column pre-swizzled: col = (slot ^ (row&7))*8 elements.
  auto stage = [&](int buf, int t) {
    const int k0 = t * 64;
    #pragma unroll
    for (int l = 0; l < 4; l++) {
      const int idx = l * 512 + tid;
      const int row = idx >> 3, slot = idx & 7;
      const int col = (slot ^ (row & 7)) * 8;
      async_copy16(A + (size_t)(m0 + row) * K + k0 + col, &Al[buf][idx * 8]);
    }
    #pragma unroll
    for (int l = 0; l < 4; l++) {
      const int idx = l * 512 + tid;
      const int row = idx >> 3, slot = idx & 7;
      const int col = (slot ^ (row & 7)) * 8;
      async_copy16(Bt + (size_t)(n0 + row) * K + k0 + col, &Bl[buf][idx * 8]);
    }
  };

  // prologue: tiles 0,1 in flight; wait tile 0 only.
  stage(0, 0);
  stage(1, 1);
  asm volatile("s_waitcnt vmcnt(8)" ::: "memory");
  __builtin_amdgcn_s_barrier();
  __builtin_amdgcn_sched_barrier(0);

  for (int t = 0; t < NT; t++) {
    const int cur = t & 1;

    // ---- (1) issue the wave's full A/B fragment reads ----
    bf16x8 af[8][2], bfr[4][2];
    #pragma unroll
    for (int j = 0; j < 4; j++) {
      const int rowl = wc * 64 + j * 16 + lr;
      #pragma unroll
      for (int kh = 0; kh < 2; kh++) {
        const int c = kh * 4 + quad;
        bfr[j][kh] = *(const bf16x8*)&Bl[cur][rowl * 64 + ((c ^ (rowl & 7)) * 8)];
      }
    }
    #pragma unroll
    for (int i = 0; i < 8; i++) {
      const int rowl = wr * 128 + i * 16 + lr;
      #pragma unroll
      for (int kh = 0; kh < 2; kh++) {
        const int c = kh * 4 + quad;
        af[i][kh] = *(const bf16x8*)&Al[cur][rowl * 64 + ((c ^ (rowl & 7)) * 8)];
      }
    }

    // ---- (2) 64 MFMA; compiler interleaves lgkmcnt(N) waits with reads ----
    __builtin_amdgcn_s_setprio(1);
    #pragma unroll
    for (int kh = 0; kh < 2; kh++)
      #pragma unroll
      for (int i = 0; i < 8; i++)
        #pragma unroll
        for (int j = 0; j < 4; j++)
          acc[i][j] = __builtin_amdgcn_mfma_f32_16x16x32_bf16(
              af[i][kh], bfr[j][kh], acc[i][j], 0, 0, 0);
    __builtin_amdgcn_s_setprio(0);

    // ---- (3) WAR fence: buf[cur] fully consumed ----
    asm volatile("s_waitcnt lgkmcnt(0)" ::: "memory");
    __builtin_amdgcn_sched_barrier(0);
    __builtin_amdgcn_s_barrier();
    __builtin_amdgcn_sched_barrier(0);

    // ---- (4) stage t+2 into freed buf; counted wait confirms t+1 ----
    if (t + 2 < NT) {
      stage(cur, t + 2);
      asm volatile("s_waitcnt vmcnt(8)" ::: "memory");   // t+1 (own) landed
    } else if (t + 1 < NT) {
      asm volatile("s_waitcnt vmcnt(0)" ::: "memory");   // tail
    }

    // ---- (5) end barrier: every wave passed its vmcnt -> t+1 visible ----
    __builtin_amdgcn_sched_barrier(0);
    __builtin_amdgcn_s_barrier();
    __builtin_amdgcn_sched_barrier(0);
  }

  // ---- epilogue: C/D layout col = lane&15, row = quad*4 + r ----
  #pragma unroll
  for (int mi = 0; mi < 8; mi++) {
    int grow = m0 + wr * 128 + mi * 16 + quad * 4;
    #pragma unroll
    for (int nj = 0; nj < 4; nj++) {
      int gc = n0 + wc * 64 + nj * 16 + lr;
      if (EPI == 0) {
        bf16* outp = (bf16*)Out;
        int dh = gc & (DD - 1);
        float sgn = (gc & 1) ? 1.0f : -1.0f;
        #pragma unroll
        for (int r = 0; r < 4; r++) {
          float x  = acc[mi][nj][r];
          float xp = __shfl_xor(x, 1, 64);
          int tq = (grow + r) & (TT - 1);
          float s = sinp[tq * DD + dh];
          float c = cosp[tq * DD + dh];
          outp[(size_t)(grow + r) * N + gc] = (bf16)(x * c + sgn * xp * s);
        }
      } else if (EPI == 1) {
        bf16* outp = (bf16*)Out;
        int hh = gc >> 7, dh = gc & (DD - 1);
        int bidx = grow >> 11, tq = grow & (TT - 1);
        bf16x4 w;
        #pragma unroll
        for (int r = 0; r < 4; r++) w[r] = (bf16)acc[mi][nj][r];
        *(bf16x4*)(outp + (((size_t)bidx * HH + hh) * DD + dh) * TT + tq) = w;
      } else {
        float* outp = (float*)Out;
        #pragma unroll
        for (int r = 0; r < 4; r++)
          outp[(size_t)(grow + r) * N + gc] = acc[mi][nj][r];
      }
    }
  }
}

// ---------------------------------------------------------------------------
// Flash attention v3 + T1 XCD swizzle: 4 waves/block, 64 q-rows/block,
// 64-key K/V tiles, double-buffered LDS via global_load_lds with
// prefetch-before-compute -> ONE __syncthreads/tile.  XCD swizzle groups
// the 32 q-blocks of one (b,h) on a single XCD so K/V (1 MB) stays in
// that XCD's L2 across blocks.
// Softmax: exp2-domain, lane-local deferred-max guard, row-sum via
// all-ones MFMA.  XOR-swizzled LDS (16B granule).
// ---------------------------------------------------------------------------
__global__ __launch_bounds__(256) void attn_k(
    const bf16* __restrict__ qb, const bf16* __restrict__ kb,
    const bf16* __restrict__ vt, bf16* __restrict__ ao)
{
  const int tid  = threadIdx.x;
  const int wave = tid >> 6, lane = tid & 63;
  const int lr   = lane & 15, quad = lane >> 4;

  // T1 XCD swizzle: 2048 blocks, chunk = 256.  XCD g gets tiles
  // g*256..g*256+255 = 8 full (b,h) K/V working sets, 32 q-blocks each.
  const int dflat = ((blockIdx.z * HH) + blockIdx.y) * (TT / 64) + blockIdx.x;
  const int tileid = (dflat & 7) * 256 + (dflat >> 3);
  const int bxq  = tileid & 31;            // q-block index
  const int h    = (tileid >> 5) & (HH - 1);
  const int b    = tileid >> 10;

  const int qblk = bxq * 64;
  const int q0   = qblk + wave * 16;       // this wave's 16 q-rows

  // Kl[sel] row k (256B): slot s (16B) holds K[k][(s ^ (k&15))*8 ..]
  // Vl[sel] row d (128B): slot s (16B) holds Vt[d][(s ^ (d&7))*8 ..]  (cols=t)
  __shared__ bf16 Kl[2][64 * 128];
  __shared__ bf16 Vl[2][128 * 64];
  __shared__ bf16 Pl[4][16][72];           // per-wave P (16B-aligned rows)

  // Q fragments (A-layout): lane holds Q[q0+lr][quad*8+j + 32*ds]
  bf16x8 qf[4];
  const bf16* qrow = qb + ((size_t)(b * TT + q0 + lr) * HH + h) * DD;
  #pragma unroll
  for (int ds = 0; ds < 4; ds++) qf[ds] = *(const bf16x8*)(qrow + ds * 32 + quad * 8);

  float m_r[4];
  f32x4 lacc;                              // row-sum accumulator (via ones-MFMA)
  f32x4 oacc[8];
  #pragma unroll
  for (int r = 0; r < 4; r++) { m_r[r] = -1e30f; lacc[r] = 0.f; }
  #pragma unroll
  for (int dc = 0; dc < 8; dc++) oacc[dc] = f32x4{0.f, 0.f, 0.f, 0.f};

  const int jt_end = bxq;                  // inclusive (causal)
  const float sc2 = 0.12753861f;           // (1/sqrt(128)) * log2(e)

  const bf16* kbase = kb + ((size_t)(b * TT) * HH + h) * DD;
  const bf16* vbase = vt + ((size_t)b * HH + h) * DD * TT;

  // staging geometry (per wave, 4 instrs each for K and V):
  const int k_row_in = lane >> 4;          // 0..3   (4 rows of 256B per chunk)
  const int k_slot   = lane & 15;
  const int v_row_in = lane >> 3;          // 0..7   (8 rows of 128B per chunk)
  const int v_slot   = lane & 7;

  auto stage = [&](int sel, int jt) {
    const int k0 = jt * 64;
    #pragma unroll
    for (int s = 0; s < 4; s++) {
      const int ch   = s * 4 + wave;       // 0..15
      const int krow = ch * 4 + k_row_in;  // 0..63
      const int kcol = (k_slot ^ (krow & 15)) * 8;
      async_copy16(kbase + (size_t)(k0 + krow) * (HH * DD) + kcol,
                   &Kl[sel][ch * 512 + lane * 8]);
      const int drow = ch * 8 + v_row_in;  // 0..127
      const int vcol = (v_slot ^ (drow & 7)) * 8;
      async_copy16(vbase + (size_t)drow * TT + k0 + vcol,
                   &Vl[sel][ch * 512 + lane * 8]);
    }
  };

  bf16x8 ones;
  #pragma unroll
  for (int t = 0; t < 8; t++) ones[t] = (bf16)1.0f;

  // prologue: stage tile 0, drain.
  stage(0, 0);
  __syncthreads();

  for (int jt = 0; jt <= jt_end; jt++) {
    const int cur = jt & 1;
    if (jt < jt_end) stage(cur ^ 1, jt + 1);   // prefetch next tile (other buf)
    const int k0 = jt * 64;

    // ---- QK^T: 4 key groups of 16 ----
    f32x4 sacc[4];
    #pragma unroll
    for (int kk = 0; kk < 4; kk++) sacc[kk] = f32x4{0.f, 0.f, 0.f, 0.f};
    __builtin_amdgcn_s_setprio(1);
    #pragma unroll
    for (int ds = 0; ds < 4; ds++) {
      #pragma unroll
      for (int kk = 0; kk < 4; kk++) {
        const int key  = 16 * kk + lr;
        const int slot = (ds * 4 + quad) ^ lr;        // lr == key&15
        bf16x8 kf = *(const bf16x8*)&Kl[cur][key * 128 + slot * 8];
        sacc[kk] = __builtin_amdgcn_mfma_f32_16x16x32_bf16(qf[ds], kf, sacc[kk], 0, 0, 0);
      }
    }
    __builtin_amdgcn_s_setprio(0);

    // ---- softmax (raw-score domain; exp2 with folded scale) ----
    const int qr = q0 + quad * 4;
    float v[4][4], lmx[4];
    if (jt == jt_end) {                    // only the diagonal tile masks
      #pragma unroll
      for (int r = 0; r < 4; r++)
        #pragma unroll
        for (int kk = 0; kk < 4; kk++) {
          float x = sacc[kk][r];
          if (k0 + 16 * kk + lr > qr + r) x = -1e30f;
          v[r][kk] = x;
        }
    } else {
      #pragma unroll
      for (int r = 0; r < 4; r++)
        #pragma unroll
        for (int kk = 0; kk < 4; kk++) v[r][kk] = sacc[kk][r];
    }
    bool need = false;
    #pragma unroll
    for (int r = 0; r < 4; r++) {
      lmx[r] = fmaxf(fmaxf(v[r][0], v[r][1]), fmaxf(v[r][2], v[r][3]));
      need = need || (lmx[r] > m_r[r] + 24.0f);   // e bounded by 2^(24*sc2)≈8.4
    }
    if (__any(need)) {                     // rare: full reduce + rescale
      #pragma unroll
      for (int r = 0; r < 4; r++) {
        float mx = lmx[r];
        #pragma unroll
        for (int off = 1; off < 16; off <<= 1) mx = fmaxf(mx, __shfl_xor(mx, off, 64));
        float mn = fmaxf(m_r[r], mx);
        float al = __builtin_amdgcn_exp2f((m_r[r] - mn) * sc2);
        lacc[r] *= al;
        #pragma unroll
        for (int dc = 0; dc < 8; dc++) oacc[dc][r] *= al;
        m_r[r] = mn;
      }
    }
    #pragma unroll
    for (int r = 0; r < 4; r++) {
      const float mb = m_r[r] * sc2;
      #pragma unroll
      for (int kk = 0; kk < 4; kk++) {
        float e = __builtin_amdgcn_exp2f(__builtin_fmaf(v[r][kk], sc2, -mb));
        Pl[wave][quad * 4 + r][kk * 16 + lr] = (bf16)e;
      }
    }

    // wave-private P: only in-wave DS ordering needed (no block barrier)
    asm volatile("s_waitcnt lgkmcnt(0)" ::: "memory");
    __builtin_amdgcn_sched_barrier(0);

    // ---- PV: P[16x64] @ V[64x128]; row-sum l via all-ones B-frag ----
    bf16x8 pf0 = *(const bf16x8*)&Pl[wave][lr][quad * 8];
    bf16x8 pf1 = *(const bf16x8*)&Pl[wave][lr][32 + quad * 8];
    __builtin_amdgcn_s_setprio(1);
    lacc = __builtin_amdgcn_mfma_f32_16x16x32_bf16(pf0, ones, lacc, 0, 0, 0);
    lacc = __builtin_amdgcn_mfma_f32_16x16x32_bf16(pf1, ones, lacc, 0, 0, 0);
    #pragma unroll
    for (int dc = 0; dc < 8; dc++) {
      const int d  = dc * 16 + lr;
      const int s0 = (quad)     ^ (lr & 7);
      const int s1 = (4 + quad) ^ (lr & 7);
      bf16x8 vf0 = *(const bf16x8*)&Vl[cur][d * 64 + s0 * 8];
      bf16x8 vf1 = *(const bf16x8*)&Vl[cur][d * 64 + s1 * 8];
      oacc[dc] = __builtin_amdgcn_mfma_f32_16x16x32_bf16(pf0, vf0, oacc[dc], 0, 0, 0);
      oacc[dc] = __builtin_amdgcn_mfma_f32_16x16x32_bf16(pf1, vf1, oacc[dc], 0, 0, 0);
    }
    __builtin_amdgcn_s_setprio(0);

    // single barrier per tile: drains prefetch (vmcnt) + WAR for next stage
    __syncthreads();
  }

  float inv[4];
  #pragma unroll
  for (int r = 0; r < 4; r++) inv[r] = 1.0f / lacc[r];
  bf16* aor = ao + ((size_t)(b * TT + q0 + quad * 4) * HH + h) * DD + lr;
  #pragma unroll
  for (int dc = 0; dc < 8; dc++)
    #pragma unroll
    for (int r = 0; r < 4; r++)
      aor[(size_t)r * HH * DD + dc * 16] = (bf16)(oacc[dc][r] * inv[r]);
}

// ---------------------------------------------------------------------------
// ws: Ab | Wt | qb | kb | vt | ao  (bf16, 32 MB each = 192 MB)
// ---------------------------------------------------------------------------
extern "C" void kernel_launch(void* const* d_in, const int* in_sizes, int n_in,
                              void* d_out, int out_size, void* d_ws, size_t ws_size,
                              hipStream_t stream)
{
  const float* hs   = (const float*)d_in[0];
  const float* sinp = (const float*)d_in[1];
  const float* cosp = (const float*)d_in[2];
  const float* Wq   = (const float*)d_in[4];
  const float* Wk   = (const float*)d_in[5];
  const float* Wv   = (const float*)d_in[6];
  const float* Wo   = (const float*)d_in[7];

  const size_t NE = (size_t)MM * CC;
  bf16* Ab = (bf16*)d_ws;
  bf16* Wt = Ab + NE;
  bf16* qb = Wt + NE;
  bf16* kb = qb + NE;
  bf16* vt = kb + NE;
  bf16* ao = vt + NE;

  dim3 gg(CC / 256, MM / 256), gb(512);
  dim3 gt(CC / 64, CC / 64);

  conv_k<<<NE / (256 * 8), 256, 0, stream>>>(hs, Ab);

  transpose_k<<<gt, dim3(256), 0, stream>>>(Wq, Wt);
  gemm_k<0><<<gg, gb, 0, stream>>>(Ab, Wt, qb, sinp, cosp);

  transpose_k<<<gt, dim3(256), 0, stream>>>(Wk, Wt);
  gemm_k<0><<<gg, gb, 0, stream>>>(Ab, Wt, kb, sinp, cosp);

  transpose_k<<<gt, dim3(256), 0, stream>>>(Wv, Wt);
  gemm_k<1><<<gg, gb, 0, stream>>>(Ab, Wt, vt, sinp, cosp);

  attn_k<<<dim3(TT / 64, HH, BB), dim3(256), 0, stream>>>(qb, kb, vt, ao);

  transpose_k<<<gt, dim3(256), 0, stream>>>(Wo, Wt);
  gemm_k<2><<<gg, gb, 0, stream>>>(ao, Wt, d_out, sinp, cosp);
}